// Round 7
// baseline (1131.997 us; speedup 1.0000x reference)
//
#include <hip/hip_runtime.h>
#include <math.h>

// Problem constants
#define BATCH  128
#define NIN    1152
#define DIN    8
#define NOUTC  10
#define DOUT   16
#define H1DIM  512
#define H2DIM  1024
#define PIX    784
#define NROWS  (BATCH * NOUTC)   // 1280
#define GRIDP  512               // persistent grid (<= guaranteed co-residency 4/CU*256)
#define PARTW  32
#define NPART  26                // 13 col-tiles x 2 halves in gemm3

typedef __attribute__((ext_vector_type(8))) __bf16 bf16x8;
typedef __attribute__((ext_vector_type(4))) float  f32x4;

__device__ __forceinline__ float bf2f(unsigned int u) {
    union { unsigned int i; float f; } v; v.i = u << 16; return v.f;
}
__device__ __forceinline__ ushort f2bf(float f) {
    union { float f; unsigned int i; } v; v.f = f;
    unsigned int r = v.i + 0x7FFFu + ((v.i >> 16) & 1u);
    return (ushort)(r >> 16);
}
__device__ __forceinline__ float ldin(const void* p, size_t i, int isbf) {
    return isbf ? bf2f(((const ushort*)p)[i]) : ((const float*)p)[i];
}
__device__ __forceinline__ bf16x8 ld_frag(const ushort* p) {
    uint4 u = *(const uint4*)p;
    return __builtin_bit_cast(bf16x8, u);
}
__device__ __forceinline__ float dot8(uint4 a, uint4 b) {
    float s;
    s  = bf2f(a.x & 0xffffu) * bf2f(b.x & 0xffffu);
    s += bf2f(a.x >> 16)     * bf2f(b.x >> 16);
    s += bf2f(a.y & 0xffffu) * bf2f(b.y & 0xffffu);
    s += bf2f(a.y >> 16)     * bf2f(b.y >> 16);
    s += bf2f(a.z & 0xffffu) * bf2f(b.z & 0xffffu);
    s += bf2f(a.z >> 16)     * bf2f(b.z >> 16);
    s += bf2f(a.w & 0xffffu) * bf2f(b.w & 0xffffu);
    s += bf2f(a.w >> 16)     * bf2f(b.w >> 16);
    return s;
}

struct Bufs {
    const void *w, *inc, *x, *W1, *b1, *W2, *b2, *W3, *b3;
    ushort *wcvt, *icvt, *W1c, *b1c, *b2c, *b3c, *xc, *W2T, *W3T;
    ushort *bsA, *bsB, *h1, *h2, *hatG;
    float *partials;
    unsigned int *bar;      // grid-barrier slots (zeroed host-side each call)
    void *outF;
    int haveHat;
};

union ShU {
    struct { ushort tile[32][33]; } prep;                       // 2.1 KB
    struct { uint4 hatS4[NIN * DOUT / 8]; ushort wSb[NIN];      // 36.9+2.3 KB
             float redS[4][16]; float sumS[16]; float ocS[16];
             float scaleS; } red;                               // total 39.6 KB
    struct { uint4 As4[128]; uint4 Bs4[256]; } gm;              // 6 KB
};

// ---------------------------------------------------------------------------
// software grid barrier: all GRIDP blocks co-resident (launch_bounds + LDS cap)
// ---------------------------------------------------------------------------
__device__ __forceinline__ void gsync(unsigned int* bar, unsigned int target) {
    __syncthreads();
    if (threadIdx.x == 0) {
        __threadfence();   // release: make our writes visible device-wide
        unsigned int arrived =
            __hip_atomic_fetch_add(bar, 1u, __ATOMIC_ACQ_REL, __HIP_MEMORY_SCOPE_AGENT) + 1;
        while (arrived < target) {
            __builtin_amdgcn_s_sleep(2);
            arrived = __hip_atomic_load(bar, __ATOMIC_ACQUIRE, __HIP_MEMORY_SCOPE_AGENT);
        }
    }
    __syncthreads();
    __threadfence();       // acquire: invalidate stale cache before reading others' data
}

// ---------------------------------------------------------------------------
// per-block dtype detect (1 KB of w, identical result in every block)
// ---------------------------------------------------------------------------
__device__ int detect_bf(const void* w, int* cntS) {
    int tid = threadIdx.x;
    if (tid == 0) *cntS = 0;
    __syncthreads();
    const ushort* u = (const ushort*)w;
    int c = 0;
    for (int s = tid; s < 512; s += 256) {
        int e = (u[s * 2] >> 7) & 0xFF;
        if (e >= 88 && e <= 140) c++;
    }
    atomicAdd(cntS, c);
    __syncthreads();
    return (*cntS >= 384) ? 1 : 0;
}

// ---------------------------------------------------------------------------
// phase: dtype normalization + weight transposes
// ---------------------------------------------------------------------------
__device__ void phase_prep(const Bufs& a, ShU& sh, int isbf) {
    int tid = threadIdx.x;
    // transposes: 512 W2 tiles + 800 W3 tiles
    for (int t = blockIdx.x; t < 1312; t += gridDim.x) {
        const void* in; ushort* out; int R, C, tx2, ty2;
        if (t < 512) { in = a.W2; out = a.W2T; R = H1DIM; C = H2DIM; tx2 = t % 32; ty2 = t / 32; }
        else { int t2 = t - 512; in = a.W3; out = a.W3T; R = H2DIM; C = PIX; tx2 = t2 % 25; ty2 = t2 / 25; }
        int c0 = tx2 * 32, r0 = ty2 * 32, tx = tid & 31, ty = tid >> 5;
        __syncthreads();
        for (int i = ty; i < 32; i += 8) {
            int r = r0 + i, c = c0 + tx;
            sh.prep.tile[i][tx] = (r < R && c < C) ? f2bf(ldin(in, (size_t)r * C + c, isbf)) : (ushort)0;
        }
        __syncthreads();
        for (int i = ty; i < 32; i += 8) {
            int c = c0 + i, r = r0 + tx;
            if (c < C && r < R) out[(size_t)c * R + r] = sh.prep.tile[tx][i];
        }
    }
    // flat conversions
    int g0 = blockIdx.x * 256 + tid, gs = gridDim.x * 256;
    auto cv = [&](const void* s, ushort* d, int n) {
        if (isbf) { const ushort* sp = (const ushort*)s; for (int i = g0; i < n; i += gs) d[i] = sp[i]; }
        else      { const float*  sp = (const float*) s; for (int i = g0; i < n; i += gs) d[i] = f2bf(sp[i]); }
    };
    cv(a.w,   a.wcvt, NOUTC * NIN * DOUT * DIN);
    cv(a.inc, a.icvt, BATCH * NIN * DIN);
    cv(a.W1,  a.W1c,  160 * H1DIM);
    cv(a.b1,  a.b1c,  H1DIM);
    cv(a.b2,  a.b2c,  H2DIM);
    cv(a.b3,  a.b3c,  PIX);
    cv(a.x,   a.xc,   BATCH * PIX);
}

// ---------------------------------------------------------------------------
// phase: hat[b,n,k,o] = <W[n,k,o,:], inc[b,k,:]>; 720 units of 16 batches
// ---------------------------------------------------------------------------
__device__ void phase_hat(const Bufs& a) {
    int tid = threadIdx.x;
    for (int u = blockIdx.x; u < 720; u += gridDim.x) {
        int kc = u % 9, r = u / 9, bc = r % 8, n = r / 8;
        int k = kc * 128 + (tid >> 1), oh = (tid & 1) << 3;
        const uint4* wp = (const uint4*)(a.wcvt + (((size_t)n * NIN + k) * DOUT + oh) * DIN);
        uint4 wr[8];
        #pragma unroll
        for (int j = 0; j < 8; j++) wr[j] = wp[j];
        int b0 = bc * 16;
        #pragma unroll 4
        for (int bl = 0; bl < 16; bl++) {
            int b = b0 + bl;
            uint4 iu = *(const uint4*)(a.icvt + ((size_t)b * NIN + k) * DIN);
            unsigned int h[8];
            #pragma unroll
            for (int j = 0; j < 8; j++) h[j] = f2bf(dot8(wr[j], iu));
            uint4 ov = make_uint4(h[0] | (h[1] << 16), h[2] | (h[3] << 16),
                                  h[4] | (h[5] << 16), h[6] | (h[7] << 16));
            *(uint4*)(a.hatG + (((size_t)(b * NOUTC + n) * NIN + k) * DOUT + oh)) = ov;
        }
    }
}

// ---------------------------------------------------------------------------
// one (b,n) routing reduce: c/r scale_coef + weighted k-sum + squash + bscore
// + fused decoder layer-1
// ---------------------------------------------------------------------------
__device__ void reduce_bn(const Bufs& a, ShU& sh, int isbf, int bn, int iter0,
                          const ushort* bsPrev, ushort* bsOut, ushort* h1out, int writeOut)
{
    int n = bn % NOUTC, b = bn / NOUTC, tid = threadIdx.x;
    ushort* hatS = (ushort*)sh.red.hatS4;

    if (a.haveHat) {
        const uint4* hp = (const uint4*)(a.hatG + (size_t)bn * NIN * DOUT);
        #pragma unroll
        for (int i = 0; i < 9; i++) sh.red.hatS4[tid + 256 * i] = hp[tid + 256 * i];
    } else {  // fallback: recompute hat from wcvt/icvt (L2-direct)
        const ushort* wp = a.wcvt + (size_t)n * NIN * DOUT * DIN;
        for (int idx = tid; idx < NIN * DOUT; idx += 256) {
            int k = idx >> 4;
            uint4 wu = *(const uint4*)(wp + (size_t)idx * 8);
            uint4 iu = *(const uint4*)(a.icvt + ((size_t)b * NIN + k) * DIN);
            hatS[idx] = f2bf(dot8(wu, iu));
        }
    }

    if (!iter0) {
        // r-scores: 9 threads each sum NPART partials (not all 256 redundantly)
        if (tid < 9) {
            float s = 0.f;
            for (int j = 0; j < NPART; j++)
                s += a.partials[(size_t)(b * NOUTC + tid) * PARTW + j];
            sh.red.sumS[tid] = -s;
        }
        __syncthreads();
        float mn = 1e30f, mx = -1e30f;
        #pragma unroll
        for (int n2 = 0; n2 < 9; n2++) {
            float v = sh.red.sumS[n2];
            mn = fminf(mn, v); mx = fmaxf(mx, v);
        }
        float den = fmaxf(mx - mn, 1e-6f);
        float rv = (n < 9) ? fmaxf((sh.red.sumS[n] - mn) / den, 0.5f) : 0.5f;
        for (int k = tid; k < NIN; k += 256) {
            float c = 0.5f;
            if (n < 9) {
                float vv[9], mn2 = 1e30f, mx2 = -1e30f;
                #pragma unroll
                for (int n2 = 0; n2 < 9; n2++) {
                    vv[n2] = bf2f(bsPrev[(size_t)(b * NOUTC + n2) * NIN + k]);
                    mn2 = fminf(mn2, vv[n2]); mx2 = fmaxf(mx2, vv[n2]);
                }
                float den2 = fmaxf(mx2 - mn2, 1e-6f);
                c = fmaxf((vv[n] - mn2) / den2, 0.5f);
            }
            sh.red.wSb[k] = f2bf(c * rv);
        }
    }
    __syncthreads();

    // weighted k-sum, parity decomposition (conflict-free ds_read_b128)
    int h = tid & 1, kb = tid >> 1;
    int wave = tid >> 6, lane = tid & 63;
    float acc[8];
    #pragma unroll
    for (int o = 0; o < 8; o++) acc[o] = 0.f;
    #pragma unroll
    for (int j = 0; j < 9; j++) {
        int k = kb + 128 * j;
        float w = iter0 ? 1.f : bf2f(sh.red.wSb[k]);
        bf16x8 hv = ld_frag(hatS + k * 16 + h * 8);
        #pragma unroll
        for (int o = 0; o < 8; o++) acc[o] += w * (float)hv[o];
    }
    #pragma unroll
    for (int off = 32; off >= 2; off >>= 1) {
        #pragma unroll
        for (int o = 0; o < 8; o++) acc[o] += __shfl_xor(acc[o], off);
    }
    if (lane < 2) {
        #pragma unroll
        for (int o = 0; o < 8; o++) sh.red.redS[wave][lane * 8 + o] = acc[o];
    }
    __syncthreads();
    if (tid < 16)
        sh.red.sumS[tid] = sh.red.redS[0][tid] + sh.red.redS[1][tid] +
                           sh.red.redS[2][tid] + sh.red.redS[3][tid];
    __syncthreads();
    if (tid == 0) {
        float n2 = 0.f;
        #pragma unroll
        for (int o = 0; o < 16; o++) n2 += sh.red.sumS[o] * sh.red.sumS[o];
        float nrm = sqrtf(n2);
        sh.red.scaleS = n2 / (1.f + n2) / (nrm + 1e-8f);
    }
    __syncthreads();
    if (tid < 16) {
        float oc = sh.red.scaleS * sh.red.sumS[tid];
        sh.red.ocS[tid] = oc;
        if (writeOut) {
            if (isbf) ((ushort*)a.outF)[(size_t)bn * 16 + tid] = f2bf(oc);
            else      ((float*) a.outF)[(size_t)bn * 16 + tid] = oc;
        }
    }
    __syncthreads();

    if (bsOut) {
        #pragma unroll
        for (int j = 0; j < 9; j++) {
            int k = kb + 128 * j;
            bf16x8 hv = ld_frag(hatS + k * 16 + h * 8);
            float s = 0.f;
            #pragma unroll
            for (int o = 0; o < 8; o++) s += sh.red.ocS[h * 8 + o] * (float)hv[o];
            s += __shfl_xor(s, 1);
            if (h == 0) bsOut[(size_t)bn * NIN + k] = f2bf(s);
        }
    }

    if (h1out) {
        for (int col = tid; col < H1DIM; col += 256) {
            float acc1 = bf2f(a.b1c[col]);
            #pragma unroll
            for (int i = 0; i < 16; i++)
                acc1 += sh.red.ocS[i] * bf2f(a.W1c[(size_t)(n * 16 + i) * H1DIM + col]);
            h1out[(size_t)bn * H1DIM + col] = f2bf(fmaxf(acc1, 0.f));
        }
    }
}

__device__ void phase_reduce(const Bufs& a, ShU& sh, int isbf, int iter0,
                             const ushort* bsPrev, ushort* bsOut, ushort* h1out, int writeOut) {
    for (int bn = blockIdx.x; bn < NROWS; bn += gridDim.x) {
        __syncthreads();   // protect LDS reuse across bn iterations
        reduce_bn(a, sh, isbf, bn, iter0, bsPrev, bsOut, h1out, writeOut);
    }
}

// ---------------------------------------------------------------------------
// gemm2: h2 = relu(h1 @ W2 + b2), 32x64 tiles (40 x 16 = 640)
// ---------------------------------------------------------------------------
__device__ void phase_gemm2(const Bufs& a, ShU& sh) {
    int tid = threadIdx.x, wave = tid >> 6, lane = tid & 63, quad = lane >> 4, l16 = lane & 15;
    ushort* As = (ushort*)sh.gm.As4;
    ushort* Bs = (ushort*)sh.gm.Bs4;
    for (int t = blockIdx.x; t < 640; t += gridDim.x) {
        int m0 = (t % 40) * 32, n0 = (t / 40) * 64;
        f32x4 acc[2];
        #pragma unroll
        for (int nt = 0; nt < 2; nt++)
            #pragma unroll
            for (int rg = 0; rg < 4; rg++) acc[nt][rg] = 0.f;
        int sMi = tid >> 2, sKk = (tid & 3) * 8;
        const ushort* Ap = a.h1 + (size_t)(m0 + (sMi & 31)) * H1DIM + sKk;
        const ushort* Bp = a.W2T + (size_t)(n0 + sMi) * H1DIM + sKk;
        uint4 aR = (tid < 128) ? *(const uint4*)Ap : make_uint4(0, 0, 0, 0);
        uint4 bR = *(const uint4*)Bp;
        for (int k0 = 0; k0 < H1DIM; k0 += 32) {
            __syncthreads();
            if (tid < 128) sh.gm.As4[tid] = aR;
            sh.gm.Bs4[tid] = bR;
            __syncthreads();
            if (k0 + 32 < H1DIM) {
                if (tid < 128) aR = *(const uint4*)(Ap + k0 + 32);
                bR = *(const uint4*)(Bp + k0 + 32);
            }
            int r0 = (wave & 1) * 16, c0 = (wave >> 1) * 32;
            bf16x8 af = ld_frag(As + (r0 + l16) * 32 + quad * 8);
            #pragma unroll
            for (int nt = 0; nt < 2; nt++) {
                bf16x8 bf_ = ld_frag(Bs + (c0 + nt * 16 + l16) * 32 + quad * 8);
                acc[nt] = __builtin_amdgcn_mfma_f32_16x16x32_bf16(af, bf_, acc[nt], 0, 0, 0);
            }
        }
        __syncthreads();
        int rowBase = m0 + (wave & 1) * 16 + quad * 4;
        #pragma unroll
        for (int nt = 0; nt < 2; nt++) {
            int col = n0 + (wave >> 1) * 32 + nt * 16 + l16;
            float bv = bf2f(a.b2c[col]);
            #pragma unroll
            for (int rg = 0; rg < 4; rg++) {
                float v = acc[nt][rg] + bv;
                a.h2[(size_t)(rowBase + rg) * H2DIM + col] = f2bf(fmaxf(v, 0.f));
            }
        }
    }
}

// ---------------------------------------------------------------------------
// gemm3: sigmoid(h2 @ W3 + b3) -> squared-error vs x -> partials (40x13 tiles)
// ---------------------------------------------------------------------------
__device__ void phase_gemm3(const Bufs& a, ShU& sh) {
    int tid = threadIdx.x, wave = tid >> 6, lane = tid & 63, quad = lane >> 4, l16 = lane & 15;
    ushort* As = (ushort*)sh.gm.As4;
    ushort* Bs = (ushort*)sh.gm.Bs4;
    for (int t = blockIdx.x; t < 520; t += gridDim.x) {
        int m0 = (t % 40) * 32, nIdx = t / 40, n0 = nIdx * 64;
        f32x4 acc[2];
        #pragma unroll
        for (int nt = 0; nt < 2; nt++)
            #pragma unroll
            for (int rg = 0; rg < 4; rg++) acc[nt][rg] = 0.f;
        int sMi = tid >> 2, sKk = (tid & 3) * 8;
        const ushort* Ap = a.h2 + (size_t)(m0 + (sMi & 31)) * H2DIM + sKk;
        const ushort* Bp = a.W3T + (size_t)(n0 + sMi) * H2DIM + sKk;
        bool bOK = (n0 + sMi) < PIX;
        uint4 aR = (tid < 128) ? *(const uint4*)Ap : make_uint4(0, 0, 0, 0);
        uint4 bR = bOK ? *(const uint4*)Bp : make_uint4(0, 0, 0, 0);
        for (int k0 = 0; k0 < H2DIM; k0 += 32) {
            __syncthreads();
            if (tid < 128) sh.gm.As4[tid] = aR;
            sh.gm.Bs4[tid] = bR;
            __syncthreads();
            if (k0 + 32 < H2DIM) {
                if (tid < 128) aR = *(const uint4*)(Ap + k0 + 32);
                if (bOK) bR = *(const uint4*)(Bp + k0 + 32);
            }
            int r0 = (wave & 1) * 16, c0 = (wave >> 1) * 32;
            bf16x8 af = ld_frag(As + (r0 + l16) * 32 + quad * 8);
            #pragma unroll
            for (int nt = 0; nt < 2; nt++) {
                bf16x8 bf_ = ld_frag(Bs + (c0 + nt * 16 + l16) * 32 + quad * 8);
                acc[nt] = __builtin_amdgcn_mfma_f32_16x16x32_bf16(af, bf_, acc[nt], 0, 0, 0);
            }
        }
        __syncthreads();
        int rowBase = m0 + (wave & 1) * 16 + quad * 4;
        float vr[4] = {0.f, 0.f, 0.f, 0.f};
        #pragma unroll
        for (int nt = 0; nt < 2; nt++) {
            int col = n0 + (wave >> 1) * 32 + nt * 16 + l16;
            if (col < PIX) {
                float bv = bf2f(a.b3c[col]);
                #pragma unroll
                for (int rg = 0; rg < 4; rg++) {
                    int row = rowBase + rg;
                    int bb = row / NOUTC;
                    float z = acc[nt][rg] + bv;
                    float s = 1.f / (1.f + __expf(-z));
                    float d = bf2f(a.xc[(size_t)bb * PIX + col]) - s;
                    vr[rg] += d * d;
                }
            }
        }
        #pragma unroll
        for (int rg = 0; rg < 4; rg++) {
            float v = vr[rg];
            #pragma unroll
            for (int off = 8; off >= 1; off >>= 1) v += __shfl_xor(v, off, 16);
            if (l16 == 0)
                a.partials[(size_t)(rowBase + rg) * PARTW + nIdx * 2 + (wave >> 1)] = v;
        }
    }
}

// ---------------------------------------------------------------------------
// the persistent mega kernel: all phases, software grid barriers between
// ---------------------------------------------------------------------------
__global__ __launch_bounds__(256, 4) void mega_kernel(Bufs a)
{
    __shared__ ShU sh;
    __shared__ int cntS;
    unsigned int tgt = gridDim.x;
    int bslot = 0;

    int isbf = detect_bf(a.w, &cntS);
    phase_prep(a, sh, isbf);
    gsync(a.bar + bslot++, tgt);

    if (a.haveHat) {
        phase_hat(a);
        gsync(a.bar + bslot++, tgt);
    }

    phase_reduce(a, sh, isbf, 1, nullptr, a.bsA, a.h1, 0);
    gsync(a.bar + bslot++, tgt);

    for (int it = 0; it < 2; it++) {
        phase_gemm2(a, sh);
        gsync(a.bar + bslot++, tgt);
        phase_gemm3(a, sh);
        gsync(a.bar + bslot++, tgt);
        int last = (it == 1);
        phase_reduce(a, sh, isbf, 0,
                     (it == 0) ? a.bsA : a.bsB,
                     last ? nullptr : a.bsB,
                     last ? nullptr : a.h1,
                     last);
        if (!last) gsync(a.bar + bslot++, tgt);
    }
}

// ---------------------------------------------------------------------------
extern "C" void kernel_launch(void* const* d_in, const int* in_sizes, int n_in,
                              void* d_out, int out_size, void* d_ws, size_t ws_size,
                              hipStream_t stream)
{
    char* p = (char*)d_ws;
    auto alloc = [&](size_t bytes) { void* r = p; p += (bytes + 255) & ~(size_t)255; return r; };

    Bufs a;
    a.w  = d_in[2];  a.inc = d_in[0]; a.x  = d_in[1];
    a.W1 = d_in[3];  a.b1  = d_in[4];
    a.W2 = d_in[5];  a.b2  = d_in[6];
    a.W3 = d_in[7];  a.b3  = d_in[8];

    a.bar      = (unsigned int*)alloc(256);
    a.bsA      = (ushort*)alloc((size_t)NROWS * NIN * 2);
    a.bsB      = (ushort*)alloc((size_t)NROWS * NIN * 2);
    a.partials = (float*) alloc((size_t)NROWS * PARTW * 4);
    a.h1       = (ushort*)alloc((size_t)NROWS * H1DIM * 2);
    a.h2       = (ushort*)alloc((size_t)NROWS * H2DIM * 2);
    a.W2T      = (ushort*)alloc((size_t)H2DIM * H1DIM * 2);
    a.W3T      = (ushort*)alloc((size_t)PIX * H2DIM * 2);
    a.wcvt     = (ushort*)alloc((size_t)NOUTC * NIN * DOUT * DIN * 2);
    a.icvt     = (ushort*)alloc((size_t)BATCH * NIN * DIN * 2);
    a.W1c      = (ushort*)alloc((size_t)160 * H1DIM * 2);
    a.b1c      = (ushort*)alloc((size_t)H1DIM * 2);
    a.b2c      = (ushort*)alloc((size_t)H2DIM * 2);
    a.b3c      = (ushort*)alloc((size_t)PIX * 2);
    a.xc       = (ushort*)alloc((size_t)BATCH * PIX * 2);
    a.hatG     = (ushort*)alloc((size_t)NROWS * NIN * DOUT * 2);  // 47 MB, LAST
    a.haveHat  = (((char*)a.hatG + (size_t)NROWS * NIN * DOUT * 2) <=
                  ((char*)d_ws + ws_size)) ? 1 : 0;
    a.outF = d_out;

    // zero the grid-barrier slots (ws is poisoned 0xAA before every timed call)
    hipMemsetAsync(a.bar, 0, 256, stream);

    mega_kernel<<<GRIDP, 256, 0, stream>>>(a);
}

// Round 8
// 519.996 us; speedup vs baseline: 2.1769x; 2.1769x over previous
//
#include <hip/hip_runtime.h>
#include <math.h>

// Problem constants
#define BATCH  128
#define NIN    1152
#define DIN    8
#define NOUTC  10
#define DOUT   16
#define H1DIM  512
#define H2DIM  1024
#define PIX    784
#define NROWS  (BATCH * NOUTC)   // 1280
#define GRIDP  512               // persistent grid; capacity 4 blk/CU * 256 = 1024 >= 512
#define PARTW  32
#define NPART  26                // 13 col-tiles x 2 halves in gemm3

typedef __attribute__((ext_vector_type(8))) __bf16 bf16x8;
typedef __attribute__((ext_vector_type(4))) float  f32x4;

__device__ __forceinline__ float bf2f(unsigned int u) {
    union { unsigned int i; float f; } v; v.i = u << 16; return v.f;
}
__device__ __forceinline__ ushort f2bf(float f) {
    union { float f; unsigned int i; } v; v.f = f;
    unsigned int r = v.i + 0x7FFFu + ((v.i >> 16) & 1u);
    return (ushort)(r >> 16);
}
__device__ __forceinline__ float ldin(const void* p, size_t i, int isbf) {
    return isbf ? bf2f(((const ushort*)p)[i]) : ((const float*)p)[i];
}
__device__ __forceinline__ bf16x8 ld_frag(const ushort* p) {
    uint4 u = *(const uint4*)p;
    return __builtin_bit_cast(bf16x8, u);
}
__device__ __forceinline__ float dot8(uint4 a, uint4 b) {
    float s;
    s  = bf2f(a.x & 0xffffu) * bf2f(b.x & 0xffffu);
    s += bf2f(a.x >> 16)     * bf2f(b.x >> 16);
    s += bf2f(a.y & 0xffffu) * bf2f(b.y & 0xffffu);
    s += bf2f(a.y >> 16)     * bf2f(b.y >> 16);
    s += bf2f(a.z & 0xffffu) * bf2f(b.z & 0xffffu);
    s += bf2f(a.z >> 16)     * bf2f(b.z >> 16);
    s += bf2f(a.w & 0xffffu) * bf2f(b.w & 0xffffu);
    s += bf2f(a.w >> 16)     * bf2f(b.w >> 16);
    return s;
}

struct Bufs {
    const void *w, *inc, *x, *W1, *b1, *W2, *b2, *W3, *b3;
    ushort *wcvt, *icvt, *W1c, *b1c, *b2c, *b3c, *xc, *W2T, *W3T;
    ushort *bsA, *bsB, *h1, *h2, *hatG;
    float *partials;
    unsigned int *bar;      // grid-barrier slots (zeroed via hipMemsetAsync each call)
    void *outF;
    int haveHat;
};

union ShU {
    struct { ushort tile[32][33]; } prep;                       // 2.1 KB
    struct { uint4 hatS4[NIN * DOUT / 8]; ushort wSb[NIN];      // 36.9+2.3 KB
             float redS[4][16]; float sumS[16]; float ocS[16];
             float scaleS; } red;                               // total 39.6 KB
    struct { uint4 As4[128]; uint4 Bs4[256]; } gm;              // 6 KB
};

// ---------------------------------------------------------------------------
// software grid barrier, v2.
// KEY: the spin poll is RELAXED (plain sc0/sc1 load, NO cache-invalidate).
// Round 7's ACQUIRE-per-poll emitted L2 invalidations continuously from 512
// spinners, nuking every XCD's L2 while other blocks worked (1.1 ms, 97% idle).
// Fences happen ONCE per block per barrier, on the thread-0 wave only.
// ---------------------------------------------------------------------------
__device__ __forceinline__ void gsync(unsigned int* bar, unsigned int target) {
    __syncthreads();
    if (threadIdx.x == 0) {
        __builtin_amdgcn_fence(__ATOMIC_RELEASE, "agent");   // L2 writeback, once
        __hip_atomic_fetch_add(bar, 1u, __ATOMIC_RELAXED, __HIP_MEMORY_SCOPE_AGENT);
        while (__hip_atomic_load(bar, __ATOMIC_RELAXED, __HIP_MEMORY_SCOPE_AGENT) < target)
            __builtin_amdgcn_s_sleep(16);                    // ~1024 cyc between polls
        __builtin_amdgcn_fence(__ATOMIC_ACQUIRE, "agent");   // invalidate, once
    }
    __syncthreads();
}

// ---------------------------------------------------------------------------
// per-block dtype detect (1 KB of w, identical result in every block)
// ---------------------------------------------------------------------------
__device__ int detect_bf(const void* w, int* cntS) {
    int tid = threadIdx.x;
    if (tid == 0) *cntS = 0;
    __syncthreads();
    const ushort* u = (const ushort*)w;
    int c = 0;
    for (int s = tid; s < 512; s += 256) {
        int e = (u[s * 2] >> 7) & 0xFF;
        if (e >= 88 && e <= 140) c++;
    }
    atomicAdd(cntS, c);
    __syncthreads();
    return (*cntS >= 384) ? 1 : 0;
}

// ---------------------------------------------------------------------------
// phase: dtype normalization + weight transposes
// ---------------------------------------------------------------------------
__device__ void phase_prep(const Bufs& a, ShU& sh, int isbf) {
    int tid = threadIdx.x;
    for (int t = blockIdx.x; t < 1312; t += gridDim.x) {
        const void* in; ushort* out; int R, C, tx2, ty2;
        if (t < 512) { in = a.W2; out = a.W2T; R = H1DIM; C = H2DIM; tx2 = t % 32; ty2 = t / 32; }
        else { int t2 = t - 512; in = a.W3; out = a.W3T; R = H2DIM; C = PIX; tx2 = t2 % 25; ty2 = t2 / 25; }
        int c0 = tx2 * 32, r0 = ty2 * 32, tx = tid & 31, ty = tid >> 5;
        __syncthreads();
        for (int i = ty; i < 32; i += 8) {
            int r = r0 + i, c = c0 + tx;
            sh.prep.tile[i][tx] = (r < R && c < C) ? f2bf(ldin(in, (size_t)r * C + c, isbf)) : (ushort)0;
        }
        __syncthreads();
        for (int i = ty; i < 32; i += 8) {
            int c = c0 + i, r = r0 + tx;
            if (c < C && r < R) out[(size_t)c * R + r] = sh.prep.tile[tx][i];
        }
    }
    int g0 = blockIdx.x * 256 + tid, gs = gridDim.x * 256;
    auto cv = [&](const void* s, ushort* d, int n) {
        if (isbf) { const ushort* sp = (const ushort*)s; for (int i = g0; i < n; i += gs) d[i] = sp[i]; }
        else      { const float*  sp = (const float*) s; for (int i = g0; i < n; i += gs) d[i] = f2bf(sp[i]); }
    };
    cv(a.w,   a.wcvt, NOUTC * NIN * DOUT * DIN);
    cv(a.inc, a.icvt, BATCH * NIN * DIN);
    cv(a.W1,  a.W1c,  160 * H1DIM);
    cv(a.b1,  a.b1c,  H1DIM);
    cv(a.b2,  a.b2c,  H2DIM);
    cv(a.b3,  a.b3c,  PIX);
    cv(a.x,   a.xc,   BATCH * PIX);
}

// ---------------------------------------------------------------------------
// phase: hat[b,n,k,o] = <W[n,k,o,:], inc[b,k,:]>; 720 units of 16 batches
// ---------------------------------------------------------------------------
__device__ void phase_hat(const Bufs& a) {
    int tid = threadIdx.x;
    for (int u = blockIdx.x; u < 720; u += gridDim.x) {
        int kc = u % 9, r = u / 9, bc = r % 8, n = r / 8;
        int k = kc * 128 + (tid >> 1), oh = (tid & 1) << 3;
        const uint4* wp = (const uint4*)(a.wcvt + (((size_t)n * NIN + k) * DOUT + oh) * DIN);
        uint4 wr[8];
        #pragma unroll
        for (int j = 0; j < 8; j++) wr[j] = wp[j];
        int b0 = bc * 16;
        #pragma unroll 4
        for (int bl = 0; bl < 16; bl++) {
            int b = b0 + bl;
            uint4 iu = *(const uint4*)(a.icvt + ((size_t)b * NIN + k) * DIN);
            unsigned int h[8];
            #pragma unroll
            for (int j = 0; j < 8; j++) h[j] = f2bf(dot8(wr[j], iu));
            uint4 ov = make_uint4(h[0] | (h[1] << 16), h[2] | (h[3] << 16),
                                  h[4] | (h[5] << 16), h[6] | (h[7] << 16));
            *(uint4*)(a.hatG + (((size_t)(b * NOUTC + n) * NIN + k) * DOUT + oh)) = ov;
        }
    }
}

// ---------------------------------------------------------------------------
// one (b,n) routing reduce: c/r scale_coef + weighted k-sum + squash + bscore
// + fused decoder layer-1
// ---------------------------------------------------------------------------
__device__ void reduce_bn(const Bufs& a, ShU& sh, int isbf, int bn, int iter0,
                          const ushort* bsPrev, ushort* bsOut, ushort* h1out, int writeOut)
{
    int n = bn % NOUTC, b = bn / NOUTC, tid = threadIdx.x;
    ushort* hatS = (ushort*)sh.red.hatS4;

    if (a.haveHat) {
        const uint4* hp = (const uint4*)(a.hatG + (size_t)bn * NIN * DOUT);
        #pragma unroll
        for (int i = 0; i < 9; i++) sh.red.hatS4[tid + 256 * i] = hp[tid + 256 * i];
    } else {
        const ushort* wp = a.wcvt + (size_t)n * NIN * DOUT * DIN;
        for (int idx = tid; idx < NIN * DOUT; idx += 256) {
            int k = idx >> 4;
            uint4 wu = *(const uint4*)(wp + (size_t)idx * 8);
            uint4 iu = *(const uint4*)(a.icvt + ((size_t)b * NIN + k) * DIN);
            hatS[idx] = f2bf(dot8(wu, iu));
        }
    }

    if (!iter0) {
        if (tid < 9) {
            float s = 0.f;
            for (int j = 0; j < NPART; j++)
                s += a.partials[(size_t)(b * NOUTC + tid) * PARTW + j];
            sh.red.sumS[tid] = -s;
        }
        __syncthreads();
        float mn = 1e30f, mx = -1e30f;
        #pragma unroll
        for (int n2 = 0; n2 < 9; n2++) {
            float v = sh.red.sumS[n2];
            mn = fminf(mn, v); mx = fmaxf(mx, v);
        }
        float den = fmaxf(mx - mn, 1e-6f);
        float rv = (n < 9) ? fmaxf((sh.red.sumS[n] - mn) / den, 0.5f) : 0.5f;
        for (int k = tid; k < NIN; k += 256) {
            float c = 0.5f;
            if (n < 9) {
                float vv[9], mn2 = 1e30f, mx2 = -1e30f;
                #pragma unroll
                for (int n2 = 0; n2 < 9; n2++) {
                    vv[n2] = bf2f(bsPrev[(size_t)(b * NOUTC + n2) * NIN + k]);
                    mn2 = fminf(mn2, vv[n2]); mx2 = fmaxf(mx2, vv[n2]);
                }
                float den2 = fmaxf(mx2 - mn2, 1e-6f);
                c = fmaxf((vv[n] - mn2) / den2, 0.5f);
            }
            sh.red.wSb[k] = f2bf(c * rv);
        }
    }
    __syncthreads();

    // weighted k-sum, parity decomposition (conflict-free ds_read_b128)
    int h = tid & 1, kb = tid >> 1;
    int wave = tid >> 6, lane = tid & 63;
    float acc[8];
    #pragma unroll
    for (int o = 0; o < 8; o++) acc[o] = 0.f;
    #pragma unroll
    for (int j = 0; j < 9; j++) {
        int k = kb + 128 * j;
        float w = iter0 ? 1.f : bf2f(sh.red.wSb[k]);
        bf16x8 hv = ld_frag(hatS + k * 16 + h * 8);
        #pragma unroll
        for (int o = 0; o < 8; o++) acc[o] += w * (float)hv[o];
    }
    #pragma unroll
    for (int off = 32; off >= 2; off >>= 1) {
        #pragma unroll
        for (int o = 0; o < 8; o++) acc[o] += __shfl_xor(acc[o], off);
    }
    if (lane < 2) {
        #pragma unroll
        for (int o = 0; o < 8; o++) sh.red.redS[wave][lane * 8 + o] = acc[o];
    }
    __syncthreads();
    if (tid < 16)
        sh.red.sumS[tid] = sh.red.redS[0][tid] + sh.red.redS[1][tid] +
                           sh.red.redS[2][tid] + sh.red.redS[3][tid];
    __syncthreads();
    if (tid == 0) {
        float n2 = 0.f;
        #pragma unroll
        for (int o = 0; o < 16; o++) n2 += sh.red.sumS[o] * sh.red.sumS[o];
        float nrm = sqrtf(n2);
        sh.red.scaleS = n2 / (1.f + n2) / (nrm + 1e-8f);
    }
    __syncthreads();
    if (tid < 16) {
        float oc = sh.red.scaleS * sh.red.sumS[tid];
        sh.red.ocS[tid] = oc;
        if (writeOut) {
            if (isbf) ((ushort*)a.outF)[(size_t)bn * 16 + tid] = f2bf(oc);
            else      ((float*) a.outF)[(size_t)bn * 16 + tid] = oc;
        }
    }
    __syncthreads();

    if (bsOut) {
        #pragma unroll
        for (int j = 0; j < 9; j++) {
            int k = kb + 128 * j;
            bf16x8 hv = ld_frag(hatS + k * 16 + h * 8);
            float s = 0.f;
            #pragma unroll
            for (int o = 0; o < 8; o++) s += sh.red.ocS[h * 8 + o] * (float)hv[o];
            s += __shfl_xor(s, 1);
            if (h == 0) bsOut[(size_t)bn * NIN + k] = f2bf(s);
        }
    }

    if (h1out) {
        for (int col = tid; col < H1DIM; col += 256) {
            float acc1 = bf2f(a.b1c[col]);
            #pragma unroll
            for (int i = 0; i < 16; i++)
                acc1 += sh.red.ocS[i] * bf2f(a.W1c[(size_t)(n * 16 + i) * H1DIM + col]);
            h1out[(size_t)bn * H1DIM + col] = f2bf(fmaxf(acc1, 0.f));
        }
    }
}

__device__ void phase_reduce(const Bufs& a, ShU& sh, int isbf, int iter0,
                             const ushort* bsPrev, ushort* bsOut, ushort* h1out, int writeOut) {
    for (int bn = blockIdx.x; bn < NROWS; bn += gridDim.x) {
        __syncthreads();   // protect LDS reuse across bn iterations
        reduce_bn(a, sh, isbf, bn, iter0, bsPrev, bsOut, h1out, writeOut);
    }
}

// ---------------------------------------------------------------------------
// gemm2: h2 = relu(h1 @ W2 + b2), 32x64 tiles (40 x 16 = 640)
// ---------------------------------------------------------------------------
__device__ void phase_gemm2(const Bufs& a, ShU& sh) {
    int tid = threadIdx.x, wave = tid >> 6, lane = tid & 63, quad = lane >> 4, l16 = lane & 15;
    ushort* As = (ushort*)sh.gm.As4;
    ushort* Bs = (ushort*)sh.gm.Bs4;
    for (int t = blockIdx.x; t < 640; t += gridDim.x) {
        int m0 = (t % 40) * 32, n0 = (t / 40) * 64;
        f32x4 acc[2];
        #pragma unroll
        for (int nt = 0; nt < 2; nt++)
            #pragma unroll
            for (int rg = 0; rg < 4; rg++) acc[nt][rg] = 0.f;
        int sMi = tid >> 2, sKk = (tid & 3) * 8;
        const ushort* Ap = a.h1 + (size_t)(m0 + (sMi & 31)) * H1DIM + sKk;
        const ushort* Bp = a.W2T + (size_t)(n0 + sMi) * H1DIM + sKk;
        uint4 aR = (tid < 128) ? *(const uint4*)Ap : make_uint4(0, 0, 0, 0);
        uint4 bR = *(const uint4*)Bp;
        for (int k0 = 0; k0 < H1DIM; k0 += 32) {
            __syncthreads();
            if (tid < 128) sh.gm.As4[tid] = aR;
            sh.gm.Bs4[tid] = bR;
            __syncthreads();
            if (k0 + 32 < H1DIM) {
                if (tid < 128) aR = *(const uint4*)(Ap + k0 + 32);
                bR = *(const uint4*)(Bp + k0 + 32);
            }
            int r0 = (wave & 1) * 16, c0 = (wave >> 1) * 32;
            bf16x8 af = ld_frag(As + (r0 + l16) * 32 + quad * 8);
            #pragma unroll
            for (int nt = 0; nt < 2; nt++) {
                bf16x8 bf_ = ld_frag(Bs + (c0 + nt * 16 + l16) * 32 + quad * 8);
                acc[nt] = __builtin_amdgcn_mfma_f32_16x16x32_bf16(af, bf_, acc[nt], 0, 0, 0);
            }
        }
        __syncthreads();
        int rowBase = m0 + (wave & 1) * 16 + quad * 4;
        #pragma unroll
        for (int nt = 0; nt < 2; nt++) {
            int col = n0 + (wave >> 1) * 32 + nt * 16 + l16;
            float bv = bf2f(a.b2c[col]);
            #pragma unroll
            for (int rg = 0; rg < 4; rg++) {
                float v = acc[nt][rg] + bv;
                a.h2[(size_t)(rowBase + rg) * H2DIM + col] = f2bf(fmaxf(v, 0.f));
            }
        }
    }
}

// ---------------------------------------------------------------------------
// gemm3: sigmoid(h2 @ W3 + b3) -> squared-error vs x -> partials (40x13 tiles)
// ---------------------------------------------------------------------------
__device__ void phase_gemm3(const Bufs& a, ShU& sh) {
    int tid = threadIdx.x, wave = tid >> 6, lane = tid & 63, quad = lane >> 4, l16 = lane & 15;
    ushort* As = (ushort*)sh.gm.As4;
    ushort* Bs = (ushort*)sh.gm.Bs4;
    for (int t = blockIdx.x; t < 520; t += gridDim.x) {
        int m0 = (t % 40) * 32, nIdx = t / 40, n0 = nIdx * 64;
        f32x4 acc[2];
        #pragma unroll
        for (int nt = 0; nt < 2; nt++)
            #pragma unroll
            for (int rg = 0; rg < 4; rg++) acc[nt][rg] = 0.f;
        int sMi = tid >> 2, sKk = (tid & 3) * 8;
        const ushort* Ap = a.h2 + (size_t)(m0 + (sMi & 31)) * H2DIM + sKk;
        const ushort* Bp = a.W3T + (size_t)(n0 + sMi) * H2DIM + sKk;
        bool bOK = (n0 + sMi) < PIX;
        uint4 aR = (tid < 128) ? *(const uint4*)Ap : make_uint4(0, 0, 0, 0);
        uint4 bR = bOK ? *(const uint4*)Bp : make_uint4(0, 0, 0, 0);
        for (int k0 = 0; k0 < H2DIM; k0 += 32) {
            __syncthreads();
            if (tid < 128) sh.gm.As4[tid] = aR;
            sh.gm.Bs4[tid] = bR;
            __syncthreads();
            if (k0 + 32 < H2DIM) {
                if (tid < 128) aR = *(const uint4*)(Ap + k0 + 32);
                if (bOK) bR = *(const uint4*)(Bp + k0 + 32);
            }
            int r0 = (wave & 1) * 16, c0 = (wave >> 1) * 32;
            bf16x8 af = ld_frag(As + (r0 + l16) * 32 + quad * 8);
            #pragma unroll
            for (int nt = 0; nt < 2; nt++) {
                bf16x8 bf_ = ld_frag(Bs + (c0 + nt * 16 + l16) * 32 + quad * 8);
                acc[nt] = __builtin_amdgcn_mfma_f32_16x16x32_bf16(af, bf_, acc[nt], 0, 0, 0);
            }
        }
        __syncthreads();
        int rowBase = m0 + (wave & 1) * 16 + quad * 4;
        float vr[4] = {0.f, 0.f, 0.f, 0.f};
        #pragma unroll
        for (int nt = 0; nt < 2; nt++) {
            int col = n0 + (wave >> 1) * 32 + nt * 16 + l16;
            if (col < PIX) {
                float bv = bf2f(a.b3c[col]);
                #pragma unroll
                for (int rg = 0; rg < 4; rg++) {
                    int row = rowBase + rg;
                    int bb = row / NOUTC;
                    float z = acc[nt][rg] + bv;
                    float s = 1.f / (1.f + __expf(-z));
                    float d = bf2f(a.xc[(size_t)bb * PIX + col]) - s;
                    vr[rg] += d * d;
                }
            }
        }
        #pragma unroll
        for (int rg = 0; rg < 4; rg++) {
            float v = vr[rg];
            #pragma unroll
            for (int off = 8; off >= 1; off >>= 1) v += __shfl_xor(v, off, 16);
            if (l16 == 0)
                a.partials[(size_t)(rowBase + rg) * PARTW + nIdx * 2 + (wave >> 1)] = v;
        }
    }
}

// ---------------------------------------------------------------------------
// persistent mega kernel: all phases, software grid barriers between
// ---------------------------------------------------------------------------
__global__ __launch_bounds__(256, 4) void mega_kernel(Bufs a)
{
    __shared__ ShU sh;
    __shared__ int cntS;
    unsigned int tgt = gridDim.x;
    int bslot = 0;

    int isbf = detect_bf(a.w, &cntS);
    phase_prep(a, sh, isbf);
    gsync(a.bar + bslot++, tgt);

    if (a.haveHat) {
        phase_hat(a);
        gsync(a.bar + bslot++, tgt);
    }

    phase_reduce(a, sh, isbf, 1, nullptr, a.bsA, a.h1, 0);
    gsync(a.bar + bslot++, tgt);

    for (int it = 0; it < 2; it++) {
        phase_gemm2(a, sh);
        gsync(a.bar + bslot++, tgt);
        phase_gemm3(a, sh);
        gsync(a.bar + bslot++, tgt);
        int last = (it == 1);
        phase_reduce(a, sh, isbf, 0,
                     (it == 0) ? a.bsA : a.bsB,
                     last ? nullptr : a.bsB,
                     last ? nullptr : a.h1,
                     last);
        if (!last) gsync(a.bar + bslot++, tgt);
    }
}

// ---------------------------------------------------------------------------
extern "C" void kernel_launch(void* const* d_in, const int* in_sizes, int n_in,
                              void* d_out, int out_size, void* d_ws, size_t ws_size,
                              hipStream_t stream)
{
    char* p = (char*)d_ws;
    auto alloc = [&](size_t bytes) { void* r = p; p += (bytes + 255) & ~(size_t)255; return r; };

    Bufs a;
    a.w  = d_in[2];  a.inc = d_in[0]; a.x  = d_in[1];
    a.W1 = d_in[3];  a.b1  = d_in[4];
    a.W2 = d_in[5];  a.b2  = d_in[6];
    a.W3 = d_in[7];  a.b3  = d_in[8];

    a.bar      = (unsigned int*)alloc(256);
    a.bsA      = (ushort*)alloc((size_t)NROWS * NIN * 2);
    a.bsB      = (ushort*)alloc((size_t)NROWS * NIN * 2);
    a.partials = (float*) alloc((size_t)NROWS * PARTW * 4);
    a.h1       = (ushort*)alloc((size_t)NROWS * H1DIM * 2);
    a.h2       = (ushort*)alloc((size_t)NROWS * H2DIM * 2);
    a.W2T      = (ushort*)alloc((size_t)H2DIM * H1DIM * 2);
    a.W3T      = (ushort*)alloc((size_t)PIX * H2DIM * 2);
    a.wcvt     = (ushort*)alloc((size_t)NOUTC * NIN * DOUT * DIN * 2);
    a.icvt     = (ushort*)alloc((size_t)BATCH * NIN * DIN * 2);
    a.W1c      = (ushort*)alloc((size_t)160 * H1DIM * 2);
    a.b1c      = (ushort*)alloc((size_t)H1DIM * 2);
    a.b2c      = (ushort*)alloc((size_t)H2DIM * 2);
    a.b3c      = (ushort*)alloc((size_t)PIX * 2);
    a.xc       = (ushort*)alloc((size_t)BATCH * PIX * 2);
    a.hatG     = (ushort*)alloc((size_t)NROWS * NIN * DOUT * 2);  // 47 MB, LAST
    a.haveHat  = (((char*)a.hatG + (size_t)NROWS * NIN * DOUT * 2) <=
                  ((char*)d_ws + ws_size)) ? 1 : 0;
    a.outF = d_out;

    hipMemsetAsync(a.bar, 0, 256, stream);
    mega_kernel<<<GRIDP, 256, 0, stream>>>(a);
}

// Round 10
// 215.342 us; speedup vs baseline: 5.2567x; 2.4147x over previous
//
#include <hip/hip_runtime.h>
#include <math.h>

// Problem constants
#define BATCH  128
#define NIN    1152
#define DIN    8
#define NOUTC  10
#define DOUT   16
#define H1DIM  512
#define H2DIM  1024
#define PIX    784
#define NROWS  (BATCH * NOUTC)   // 1280
#define NBY3   13                // ceil(784/64) col-tiles in gemm3

typedef __attribute__((ext_vector_type(8))) __bf16 bf16x8;
typedef __attribute__((ext_vector_type(4))) float  f32x4;
typedef __attribute__((ext_vector_type(4))) unsigned int u32x4;  // nontemporal-compatible

__device__ __forceinline__ float bf2f(unsigned int u) {
    union { unsigned int i; float f; } v; v.i = u << 16; return v.f;
}
__device__ __forceinline__ ushort f2bf(float f) {
    union { float f; unsigned int i; } v; v.f = f;
    unsigned int r = v.i + 0x7FFFu + ((v.i >> 16) & 1u);
    return (ushort)(r >> 16);
}
__device__ __forceinline__ float ldin(const void* p, size_t i, int isbf) {
    return isbf ? bf2f(((const ushort*)p)[i]) : ((const float*)p)[i];
}
__device__ __forceinline__ bf16x8 ld_frag(const ushort* p) {
    uint4 u = *(const uint4*)p;
    return __builtin_bit_cast(bf16x8, u);
}
__device__ __forceinline__ float dot8(uint4 a, uint4 b) {
    float s;
    s  = bf2f(a.x & 0xffffu) * bf2f(b.x & 0xffffu);
    s += bf2f(a.x >> 16)     * bf2f(b.x >> 16);
    s += bf2f(a.y & 0xffffu) * bf2f(b.y & 0xffffu);
    s += bf2f(a.y >> 16)     * bf2f(b.y >> 16);
    s += bf2f(a.z & 0xffffu) * bf2f(b.z & 0xffffu);
    s += bf2f(a.z >> 16)     * bf2f(b.z >> 16);
    s += bf2f(a.w & 0xffffu) * bf2f(b.w & 0xffffu);
    s += bf2f(a.w >> 16)     * bf2f(b.w >> 16);
    return s;
}

// ---------------------------------------------------------------------------
// prep: dtype detect + all bf16 conversions + both weight transposes.
// blockIdx.y: 0..6 = cvt tensors, 7 = W2^T, 8 = W3^T. Each block computes the
// dtype flag locally (1 KB of w, L2-broadcast); block (0,0) publishes it.
// ---------------------------------------------------------------------------
struct PrepArgs {
    const void* src[9];   // 0:w 1:inc 2:W1 3:b1 4:b2 5:b3 6:x 7:W2 8:W3
    ushort*     dst[9];
    int         n[9];
    int*        flag;
};

__global__ __launch_bounds__(256) void prep_kernel(PrepArgs a)
{
    __shared__ int cntS;
    __shared__ ushort tile[32][33];
    int tid = threadIdx.x;
    if (tid == 0) cntS = 0;
    __syncthreads();
    {
        const ushort* wu = (const ushort*)a.src[0];
        int c = 0;
        for (int s = tid; s < 512; s += 256) {
            int e = (wu[s * 2] >> 7) & 0xFF;
            if (e >= 88 && e <= 140) c++;
        }
        atomicAdd(&cntS, c);
    }
    __syncthreads();
    int isbf = (cntS >= 384) ? 1 : 0;
    int seg = blockIdx.y;
    if (seg == 0 && blockIdx.x == 0 && tid == 0) *a.flag = isbf;

    if (seg <= 6) {
        int n = a.n[seg];
        int stride = gridDim.x * 256;
        ushort* d = a.dst[seg];
        if (isbf) {
            const ushort* s = (const ushort*)a.src[seg];
            for (int i = blockIdx.x * 256 + tid; i < n; i += stride) d[i] = s[i];
        } else {
            const float* s = (const float*)a.src[seg];
            for (int i = blockIdx.x * 256 + tid; i < n; i += stride) d[i] = f2bf(s[i]);
        }
        return;
    }
    int R = (seg == 7) ? H1DIM : H2DIM;
    int C = (seg == 7) ? H2DIM : PIX;
    int tilesX = (seg == 7) ? 32 : 25;
    int tilesY = (seg == 7) ? 16 : 32;
    int t = blockIdx.x;
    if (t >= tilesX * tilesY) return;
    int tx2 = t % tilesX, ty2 = t / tilesX;
    int c0 = tx2 * 32, r0 = ty2 * 32;
    const void* in = a.src[seg];
    ushort* out = a.dst[seg];
    int tx = tid & 31, ty = tid >> 5;
    for (int i = ty; i < 32; i += 8) {
        int r = r0 + i, c = c0 + tx;
        tile[i][tx] = (r < R && c < C) ? f2bf(ldin(in, (size_t)r * C + c, isbf)) : (ushort)0;
    }
    __syncthreads();
    for (int i = ty; i < 32; i += 8) {
        int c = c0 + i, r = r0 + tx;
        if (c < C && r < R) out[(size_t)c * R + r] = tile[tx][i];
    }
}

// ---------------------------------------------------------------------------
// hat_build: hat[b,n,k,o] = <W[n,k,o,:], inc[b,k,:]>. 8 W rows in VGPRs,
// 16 batches per block. Non-temporal stores: hat streams past L2 to LLC,
// keeping L2 free for W/inc reuse.
// ---------------------------------------------------------------------------
__global__ __launch_bounds__(256) void hat_build(
    const ushort* __restrict__ icvt,
    const ushort* __restrict__ wcvt,
    ushort* __restrict__ hatG)
{
    int kc = blockIdx.x, bc = blockIdx.y, n = blockIdx.z;
    int t  = threadIdx.x;
    int k  = kc * 128 + (t >> 1);
    int oh = (t & 1) << 3;

    const uint4* wp = (const uint4*)(wcvt + (((size_t)n * NIN + k) * DOUT + oh) * DIN);
    uint4 wr[8];
    #pragma unroll
    for (int j = 0; j < 8; j++) wr[j] = wp[j];

    int b0 = bc * 16;
    #pragma unroll 4
    for (int bl = 0; bl < 16; bl++) {
        int b = b0 + bl;
        uint4 iu = *(const uint4*)(icvt + ((size_t)b * NIN + k) * DIN);
        unsigned int h[8];
        #pragma unroll
        for (int j = 0; j < 8; j++) h[j] = f2bf(dot8(wr[j], iu));
        u32x4 ov = { h[0] | (h[1] << 16), h[2] | (h[3] << 16),
                     h[4] | (h[5] << 16), h[6] | (h[7] << 16) };
        __builtin_nontemporal_store(ov,
            (u32x4*)(hatG + (((size_t)(b * NOUTC + n) * NIN + k) * DOUT + oh)));
    }
}

// ---------------------------------------------------------------------------
// reduce_pass: one block of 512 per (b,n). LDS 39.6 KB -> 4 blocks/CU x 512
// = 2048 threads = 100% occupancy. Fuses scale_coef(c), scale_coef(r),
// weighted k-sum, squash, bscore, decoder layer-1.
// ---------------------------------------------------------------------------
template<bool COMPUTE>
__global__ __launch_bounds__(512, 8) void reduce_pass(
    const ushort* __restrict__ hatG,
    const ushort* __restrict__ icvt,
    const ushort* __restrict__ wcvt,
    const ushort* __restrict__ bsPrev,
    const float*  __restrict__ partials,   // (NROWS, 16)
    int iter0,
    const ushort* __restrict__ W1c,
    const ushort* __restrict__ b1c,
    ushort* __restrict__ h1out,
    ushort* __restrict__ bsOut,
    void*   __restrict__ outFinal,
    const int* __restrict__ flagp)
{
    int bn  = blockIdx.x;
    int n   = bn % NOUTC;
    int b   = bn / NOUTC;
    int tid = threadIdx.x;

    __shared__ uint4  hatS4[NIN * DOUT / 8];  // 36 KB
    __shared__ ushort wSb[NIN];               // 2.3 KB
    __shared__ float  redS[8][16];
    __shared__ float  sumS[16];
    __shared__ float  ocS[16];
    __shared__ float  scaleS;
    ushort* hatS = (ushort*)hatS4;

    if constexpr (COMPUTE) {
        __shared__ uint4 incS4[NIN * DIN / 8];
        const uint4* incp = (const uint4*)(icvt + (size_t)b * NIN * DIN);
        for (int i = tid; i < NIN * DIN / 8; i += 512) incS4[i] = incp[i];
        __syncthreads();
        const ushort* incS = (const ushort*)incS4;
        const ushort* wp = wcvt + (size_t)n * NIN * DOUT * DIN;
        for (int idx = tid; idx < NIN * DOUT; idx += 512) {
            int k = idx >> 4;
            uint4 wu = *(const uint4*)(wp + (size_t)idx * 8);
            uint4 iu = *(const uint4*)(incS + k * 8);
            hatS[idx] = f2bf(dot8(wu, iu));
        }
    } else {
        const u32x4* hp = (const u32x4*)(hatG + (size_t)bn * NIN * DOUT);
        for (int i = tid; i < NIN * DOUT / 8; i += 512) {
            u32x4 v = __builtin_nontemporal_load(hp + i);
            hatS4[i] = __builtin_bit_cast(uint4, v);
        }
    }

    if (!iter0) {
        if (tid < 9) {
            float s = 0.f;
            #pragma unroll
            for (int j = 0; j < NBY3; j++)
                s += partials[(size_t)(b * NOUTC + tid) * 16 + j];
            sumS[tid] = -s;
        }
        __syncthreads();
        float mn = 1e30f, mx = -1e30f;
        #pragma unroll
        for (int n2 = 0; n2 < 9; n2++) {
            float v = sumS[n2];
            mn = fminf(mn, v); mx = fmaxf(mx, v);
        }
        float den = fmaxf(mx - mn, 1e-6f);
        float rv = (n < 9) ? fmaxf((sumS[n] - mn) / den, 0.5f) : 0.5f;
        for (int k = tid; k < NIN; k += 512) {
            float c = 0.5f;
            if (n < 9) {
                float vv[9], mn2 = 1e30f, mx2 = -1e30f;
                #pragma unroll
                for (int n2 = 0; n2 < 9; n2++) {
                    vv[n2] = bf2f(bsPrev[(size_t)(b * NOUTC + n2) * NIN + k]);
                    mn2 = fminf(mn2, vv[n2]); mx2 = fmaxf(mx2, vv[n2]);
                }
                float den2 = fmaxf(mx2 - mn2, 1e-6f);
                c = fmaxf((vv[n] - mn2) / den2, 0.5f);
            }
            wSb[k] = f2bf(c * rv);
        }
    }
    __syncthreads();

    // weighted k-sum: thread owns hat row kb = tid>>1, o-half h = tid&1.
    // Consecutive lane pairs read contiguous 32 B -> conflict-free b128.
    int h = tid & 1, kb = tid >> 1;          // kb in [0,256)
    int wave = tid >> 6, lane = tid & 63;
    float acc[8];
    #pragma unroll
    for (int o = 0; o < 8; o++) acc[o] = 0.f;
    #pragma unroll
    for (int j = 0; j < 4; j++) {            // rows 0..1023
        int k = kb + 256 * j;
        float w = iter0 ? 1.f : bf2f(wSb[k]);
        bf16x8 hv = ld_frag(hatS + k * 16 + h * 8);
        #pragma unroll
        for (int o = 0; o < 8; o++) acc[o] += w * (float)hv[o];
    }
    if (kb < 128) {                          // tail rows 1024..1151
        int k = 1024 + kb;
        float w = iter0 ? 1.f : bf2f(wSb[k]);
        bf16x8 hv = ld_frag(hatS + k * 16 + h * 8);
        #pragma unroll
        for (int o = 0; o < 8; o++) acc[o] += w * (float)hv[o];
    }
    #pragma unroll
    for (int off = 32; off >= 2; off >>= 1) {
        #pragma unroll
        for (int o = 0; o < 8; o++) acc[o] += __shfl_xor(acc[o], off);
    }
    if (lane < 2) {
        #pragma unroll
        for (int o = 0; o < 8; o++) redS[wave][lane * 8 + o] = acc[o];
    }
    __syncthreads();
    if (tid < 16) {
        float s = 0.f;
        #pragma unroll
        for (int wv = 0; wv < 8; wv++) s += redS[wv][tid];
        sumS[tid] = s;
    }
    __syncthreads();
    if (tid == 0) {
        float n2 = 0.f;
        #pragma unroll
        for (int o = 0; o < 16; o++) n2 += sumS[o] * sumS[o];
        float nrm = sqrtf(n2);
        scaleS = n2 / (1.f + n2) / (nrm + 1e-8f);
    }
    __syncthreads();
    if (tid < 16) {
        float oc = scaleS * sumS[tid];
        ocS[tid] = oc;
        if (outFinal) {
            if (*flagp) ((ushort*)outFinal)[(size_t)bn * 16 + tid] = f2bf(oc);
            else        ((float*) outFinal)[(size_t)bn * 16 + tid] = oc;
        }
    }
    __syncthreads();

    if (bsOut) {
        #pragma unroll
        for (int j = 0; j < 4; j++) {
            int k = kb + 256 * j;
            bf16x8 hv = ld_frag(hatS + k * 16 + h * 8);
            float s = 0.f;
            #pragma unroll
            for (int o = 0; o < 8; o++) s += ocS[h * 8 + o] * (float)hv[o];
            s += __shfl_xor(s, 1);
            if (h == 0) bsOut[(size_t)bn * NIN + k] = f2bf(s);
        }
        if (kb < 128) {
            int k = 1024 + kb;
            bf16x8 hv = ld_frag(hatS + k * 16 + h * 8);
            float s = 0.f;
            #pragma unroll
            for (int o = 0; o < 8; o++) s += ocS[h * 8 + o] * (float)hv[o];
            s += __shfl_xor(s, 1);
            if (h == 0) bsOut[(size_t)bn * NIN + k] = f2bf(s);
        }
    }

    if (h1out) {
        int col = tid;  // 512 cols, one per thread
        float acc1 = bf2f(b1c[col]);
        #pragma unroll
        for (int i = 0; i < 16; i++)
            acc1 += ocS[i] * bf2f(W1c[(size_t)(n * 16 + i) * H1DIM + col]);
        h1out[(size_t)bn * H1DIM + col] = f2bf(fmaxf(acc1, 0.f));
    }
}

// ---------------------------------------------------------------------------
// 64x64-tile MFMA GEMM, register double-buffered staging.
// LDS rows padded to 40 ushorts (5 uint4): bank-group = (5r+q) mod 8 cycles
// all 8 groups -> ~2-way (free) instead of 8-way (2.94x) at 64 B stride.
// ---------------------------------------------------------------------------
__global__ __launch_bounds__(256) void gemm_kernel(
    const ushort* __restrict__ A, const ushort* __restrict__ Bt,
    const ushort* __restrict__ bias, int K, int N,
    ushort* __restrict__ Cout,
    const ushort* __restrict__ xin, float* __restrict__ partials)
{
    int m0 = blockIdx.x * 64, n0 = blockIdx.y * 64;
    int tid = threadIdx.x;
    int wave = tid >> 6, lane = tid & 63, quad = lane >> 4, l16 = lane & 15;

    __shared__ uint4 As4[320];   // 64 rows x 5 uint4 (chunk 4 = pad)
    __shared__ uint4 Bs4[320];
    ushort* As = (ushort*)As4;
    ushort* Bs = (ushort*)Bs4;

    f32x4 acc[4];
    #pragma unroll
    for (int nt = 0; nt < 4; nt++)
        #pragma unroll
        for (int rg = 0; rg < 4; rg++) acc[nt][rg] = 0.f;

    int sMi = tid >> 2, sKk = (tid & 3) * 8;
    int sLds = sMi * 5 + (tid & 3);
    const ushort* Ap = A + (size_t)(m0 + sMi) * K + sKk;
    const ushort* Bp = Bt + (size_t)(n0 + sMi) * K + sKk;
    bool bOK = (n0 + sMi) < N;

    uint4 aR = *(const uint4*)Ap;
    uint4 bR = bOK ? *(const uint4*)Bp : make_uint4(0, 0, 0, 0);

    for (int k0 = 0; k0 < K; k0 += 32) {
        As4[sLds] = aR;
        Bs4[sLds] = bR;
        __syncthreads();
        if (k0 + 32 < K) {
            aR = *(const uint4*)(Ap + k0 + 32);
            bR = bOK ? *(const uint4*)(Bp + k0 + 32) : make_uint4(0, 0, 0, 0);
        }
        bf16x8 a = ld_frag(As + (wave * 16 + l16) * 40 + quad * 8);
        #pragma unroll
        for (int nt = 0; nt < 4; nt++) {
            bf16x8 bb = ld_frag(Bs + (nt * 16 + l16) * 40 + quad * 8);
            acc[nt] = __builtin_amdgcn_mfma_f32_16x16x32_bf16(a, bb, acc[nt], 0, 0, 0);
        }
        __syncthreads();
    }

    int rowBase = m0 + wave * 16 + quad * 4;
    if (Cout) {
        #pragma unroll
        for (int nt = 0; nt < 4; nt++) {
            int col = n0 + nt * 16 + l16;
            float bv = bf2f(bias[col]);
            #pragma unroll
            for (int rg = 0; rg < 4; rg++) {
                float v = acc[nt][rg] + bv;
                Cout[(size_t)(rowBase + rg) * N + col] = f2bf(fmaxf(v, 0.f));
            }
        }
    } else {
        float vr[4] = {0.f, 0.f, 0.f, 0.f};
        #pragma unroll
        for (int nt = 0; nt < 4; nt++) {
            int col = n0 + nt * 16 + l16;
            if (col < N) {
                float bv = bf2f(bias[col]);
                #pragma unroll
                for (int rg = 0; rg < 4; rg++) {
                    int row = rowBase + rg;
                    int bb = row / NOUTC;
                    float z = acc[nt][rg] + bv;
                    float s = 1.f / (1.f + __expf(-z));
                    float d = bf2f(xin[(size_t)bb * PIX + col]) - s;
                    vr[rg] += d * d;
                }
            }
        }
        #pragma unroll
        for (int rg = 0; rg < 4; rg++) {
            float v = vr[rg];
            #pragma unroll
            for (int off = 8; off >= 1; off >>= 1) v += __shfl_xor(v, off, 16);
            if (l16 == 0)
                partials[(size_t)(rowBase + rg) * 16 + blockIdx.y] = v;
        }
    }
}

// ---------------------------------------------------------------------------
extern "C" void kernel_launch(void* const* d_in, const int* in_sizes, int n_in,
                              void* d_out, int out_size, void* d_ws, size_t ws_size,
                              hipStream_t stream)
{
    const void* inc = d_in[0];
    const void* x   = d_in[1];
    const void* w   = d_in[2];
    const void* W1  = d_in[3];
    const void* b1  = d_in[4];
    const void* W2  = d_in[5];
    const void* b2  = d_in[6];
    const void* W3  = d_in[7];
    const void* b3  = d_in[8];

    char* p = (char*)d_ws;
    auto alloc = [&](size_t bytes) { void* r = p; p += (bytes + 255) & ~(size_t)255; return r; };
    int*    flagWS    = (int*)alloc(256);
    ushort* bsA       = (ushort*)alloc((size_t)NROWS * NIN * 2);
    ushort* bsB       = (ushort*)alloc((size_t)NROWS * NIN * 2);
    float*  partials  = (float*)alloc((size_t)NROWS * 16 * 4);
    ushort* h1WS      = (ushort*)alloc((size_t)NROWS * H1DIM * 2);
    ushort* h2WS      = (ushort*)alloc((size_t)NROWS * H2DIM * 2);
    ushort* W2T       = (ushort*)alloc((size_t)H2DIM * H1DIM * 2);
    ushort* W3T       = (ushort*)alloc((size_t)PIX * H2DIM * 2);
    ushort* wcvt      = (ushort*)alloc((size_t)NOUTC * NIN * DOUT * DIN * 2);
    ushort* icvt      = (ushort*)alloc((size_t)BATCH * NIN * DIN * 2);
    ushort* W1c       = (ushort*)alloc((size_t)160 * H1DIM * 2);
    ushort* b1c       = (ushort*)alloc((size_t)H1DIM * 2);
    ushort* b2c       = (ushort*)alloc((size_t)H2DIM * 2);
    ushort* b3c       = (ushort*)alloc((size_t)PIX * 2);
    ushort* xc        = (ushort*)alloc((size_t)BATCH * PIX * 2);
    ushort* hatG      = (ushort*)alloc((size_t)NROWS * NIN * DOUT * 2);  // 47 MB, LAST
    bool haveHat = ((char*)hatG + (size_t)NROWS * NIN * DOUT * 2) <= ((char*)d_ws + ws_size);

    PrepArgs pa;
    pa.src[0] = w;   pa.dst[0] = wcvt; pa.n[0] = NOUTC * NIN * DOUT * DIN;
    pa.src[1] = inc; pa.dst[1] = icvt; pa.n[1] = BATCH * NIN * DIN;
    pa.src[2] = W1;  pa.dst[2] = W1c;  pa.n[2] = 160 * H1DIM;
    pa.src[3] = b1;  pa.dst[3] = b1c;  pa.n[3] = H1DIM;
    pa.src[4] = b2;  pa.dst[4] = b2c;  pa.n[4] = H2DIM;
    pa.src[5] = b3;  pa.dst[5] = b3c;  pa.n[5] = PIX;
    pa.src[6] = x;   pa.dst[6] = xc;   pa.n[6] = BATCH * PIX;
    pa.src[7] = W2;  pa.dst[7] = W2T;  pa.n[7] = 0;
    pa.src[8] = W3;  pa.dst[8] = W3T;  pa.n[8] = 0;
    pa.flag = flagWS;
    prep_kernel<<<dim3(800, 9), 256, 0, stream>>>(pa);

    if (haveHat) hat_build<<<dim3(9, 8, NOUTC), 256, 0, stream>>>(icvt, wcvt, hatG);

    // iter 0: rc = 1; writes bscore->bsA and fused layer-1 h1
    if (haveHat)
        reduce_pass<false><<<NROWS, 512, 0, stream>>>(
            hatG, icvt, wcvt, nullptr, nullptr, 1,
            W1c, b1c, h1WS, bsA, nullptr, flagWS);
    else
        reduce_pass<true><<<NROWS, 512, 0, stream>>>(
            nullptr, icvt, wcvt, nullptr, nullptr, 1,
            W1c, b1c, h1WS, bsA, nullptr, flagWS);

    for (int it = 0; it < 2; it++) {
        gemm_kernel<<<dim3(NROWS / 64, H2DIM / 64), 256, 0, stream>>>(
            h1WS, W2T, b2c, H1DIM, H2DIM, h2WS, nullptr, nullptr);
        gemm_kernel<<<dim3(NROWS / 64, NBY3), 256, 0, stream>>>(
            h2WS, W3T, b3c, H2DIM, PIX, nullptr, xc, partials);

        int last = (it == 1);
        const ushort* bsP = (it == 0) ? bsA : bsB;
        ushort* bsO       = last ? nullptr : bsB;
        ushort* h1o       = last ? nullptr : h1WS;
        void*   fin       = last ? d_out : nullptr;
        if (haveHat)
            reduce_pass<false><<<NROWS, 512, 0, stream>>>(
                hatG, icvt, wcvt, bsP, partials, 0,
                W1c, b1c, h1o, bsO, fin, flagWS);
        else
            reduce_pass<true><<<NROWS, 512, 0, stream>>>(
                nullptr, icvt, wcvt, bsP, partials, 0,
                W1c, b1c, h1o, bsO, fin, flagWS);
    }
}

// Round 11
// 213.211 us; speedup vs baseline: 5.3093x; 1.0100x over previous
//
#include <hip/hip_runtime.h>
#include <math.h>

// Problem constants
#define BATCH  128
#define NIN    1152
#define DIN    8
#define NOUTC  10
#define DOUT   16
#define H1DIM  512
#define H2DIM  1024
#define PIX    784
#define NROWS  (BATCH * NOUTC)   // 1280
#define NBY3   13                // ceil(784/64) col-tiles in gemm3

typedef __attribute__((ext_vector_type(8))) __bf16 bf16x8;
typedef __attribute__((ext_vector_type(4))) float  f32x4;
typedef __attribute__((ext_vector_type(4))) unsigned int u32x4;  // nontemporal-compatible

__device__ __forceinline__ float bf2f(unsigned int u) {
    union { unsigned int i; float f; } v; v.i = u << 16; return v.f;
}
__device__ __forceinline__ ushort f2bf(float f) {
    union { float f; unsigned int i; } v; v.f = f;
    unsigned int r = v.i + 0x7FFFu + ((v.i >> 16) & 1u);
    return (ushort)(r >> 16);
}
__device__ __forceinline__ float ldin(const void* p, size_t i, int isbf) {
    return isbf ? bf2f(((const ushort*)p)[i]) : ((const float*)p)[i];
}
__device__ __forceinline__ bf16x8 frag_of(uint4 u) {
    return __builtin_bit_cast(bf16x8, u);
}
__device__ __forceinline__ bf16x8 ld_frag(const ushort* p) {
    return frag_of(*(const uint4*)p);
}
__device__ __forceinline__ float dot8(uint4 a, uint4 b) {
    float s;
    s  = bf2f(a.x & 0xffffu) * bf2f(b.x & 0xffffu);
    s += bf2f(a.x >> 16)     * bf2f(b.x >> 16);
    s += bf2f(a.y & 0xffffu) * bf2f(b.y & 0xffffu);
    s += bf2f(a.y >> 16)     * bf2f(b.y >> 16);
    s += bf2f(a.z & 0xffffu) * bf2f(b.z & 0xffffu);
    s += bf2f(a.z >> 16)     * bf2f(b.z >> 16);
    s += bf2f(a.w & 0xffffu) * bf2f(b.w & 0xffffu);
    s += bf2f(a.w >> 16)     * bf2f(b.w >> 16);
    return s;
}
// pack 8 f32 (two float4s) into a uint4 of bf16
__device__ __forceinline__ uint4 pack8(float4 a, float4 b) {
    uint4 r;
    r.x = f2bf(a.x) | ((unsigned)f2bf(a.y) << 16);
    r.y = f2bf(a.z) | ((unsigned)f2bf(a.w) << 16);
    r.z = f2bf(b.x) | ((unsigned)f2bf(b.y) << 16);
    r.w = f2bf(b.z) | ((unsigned)f2bf(b.w) << 16);
    return r;
}

// per-block dtype detect: 1 KB of w, same answer in every block
__device__ __forceinline__ int detect_bf(const void* w, int* cntS) {
    int tid = threadIdx.x, nt = blockDim.x;
    if (tid == 0) *cntS = 0;
    __syncthreads();
    const ushort* u = (const ushort*)w;
    int c = 0;
    for (int s = tid; s < 512; s += nt) {
        int e = (u[s * 2] >> 7) & 0xFF;
        if (e >= 88 && e <= 140) c++;
    }
    atomicAdd(cntS, c);
    __syncthreads();
    return (*cntS >= 384) ? 1 : 0;
}

// ---------------------------------------------------------------------------
// prep: dtype flag publish + small-tensor conversions + weight transposes.
// blockIdx.y: 0:W1 1:b1 2:b2 3:b3 4:x 5:W2^T 6:W3^T.
// ---------------------------------------------------------------------------
struct PrepArgs {
    const void* w;
    const void* src[7];
    ushort*     dst[7];
    int         n[7];
    int*        flag;
};

__global__ __launch_bounds__(256) void prep_kernel(PrepArgs a)
{
    __shared__ int cntS;
    __shared__ ushort tile[32][33];
    int tid = threadIdx.x;
    int isbf = detect_bf(a.w, &cntS);
    int seg = blockIdx.y;
    if (seg == 0 && blockIdx.x == 0 && tid == 0) *a.flag = isbf;

    if (seg <= 4) {
        int n = a.n[seg];
        int stride = gridDim.x * 256;
        ushort* d = a.dst[seg];
        if (isbf) {
            const ushort* s = (const ushort*)a.src[seg];
            for (int i = blockIdx.x * 256 + tid; i < n; i += stride) d[i] = s[i];
        } else {
            const float* s = (const float*)a.src[seg];
            for (int i = blockIdx.x * 256 + tid; i < n; i += stride) d[i] = f2bf(s[i]);
        }
        return;
    }
    int R = (seg == 5) ? H1DIM : H2DIM;
    int C = (seg == 5) ? H2DIM : PIX;
    int tilesX = (seg == 5) ? 32 : 25;
    int tilesY = (seg == 5) ? 16 : 32;
    int t = blockIdx.x;
    if (t >= tilesX * tilesY) return;
    int tx2 = t % tilesX, ty2 = t / tilesX;
    int c0 = tx2 * 32, r0 = ty2 * 32;
    const void* in = a.src[seg];
    ushort* out = a.dst[seg];
    int tx = tid & 31, ty = tid >> 5;
    for (int i = ty; i < 32; i += 8) {
        int r = r0 + i, c = c0 + tx;
        tile[i][tx] = (r < R && c < C) ? f2bf(ldin(in, (size_t)r * C + c, isbf)) : (ushort)0;
    }
    __syncthreads();
    for (int i = ty; i < 32; i += 8) {
        int c = c0 + i, r = r0 + tx;
        if (c < C && r < R) out[(size_t)c * R + r] = tile[tx][i];
    }
}

// ---------------------------------------------------------------------------
// hat_build: hat[b,n,k,o] = <W[n,k,o,:], inc[b,k,:]> reading w/inc RAW
// (dtype-branched vector loads; f32 packed to bf16 in-register = identical
// numerics to the old wcvt path). Non-temporal stores stream hat to LLC.
// ---------------------------------------------------------------------------
__global__ __launch_bounds__(256) void hat_build(
    const void* __restrict__ inc,
    const void* __restrict__ w,
    ushort* __restrict__ hatG)
{
    __shared__ int cntS;
    int isbf = detect_bf(w, &cntS);
    int kc = blockIdx.x, bc = blockIdx.y, n = blockIdx.z;
    int t  = threadIdx.x;
    int k  = kc * 128 + (t >> 1);
    int oh = (t & 1) << 3;

    size_t wbase = ((size_t)n * NIN + k) * DOUT + oh;   // row units of 8 elems
    uint4 wr[8];
    if (isbf) {
        const uint4* wp = (const uint4*)((const ushort*)w + wbase * DIN);
        #pragma unroll
        for (int j = 0; j < 8; j++) wr[j] = wp[j];
    } else {
        const float4* wp = (const float4*)((const float*)w + wbase * DIN);
        #pragma unroll
        for (int j = 0; j < 8; j++) wr[j] = pack8(wp[2 * j], wp[2 * j + 1]);
    }

    int b0 = bc * 16;
    #pragma unroll 4
    for (int bl = 0; bl < 16; bl++) {
        int b = b0 + bl;
        size_t ioff = ((size_t)b * NIN + k) * DIN;
        uint4 iu;
        if (isbf) iu = *(const uint4*)((const ushort*)inc + ioff);
        else {
            const float4* ip = (const float4*)((const float*)inc + ioff);
            iu = pack8(ip[0], ip[1]);
        }
        unsigned int h[8];
        #pragma unroll
        for (int j = 0; j < 8; j++) h[j] = f2bf(dot8(wr[j], iu));
        u32x4 ov = { h[0] | (h[1] << 16), h[2] | (h[3] << 16),
                     h[4] | (h[5] << 16), h[6] | (h[7] << 16) };
        __builtin_nontemporal_store(ov,
            (u32x4*)(hatG + (((size_t)(b * NOUTC + n) * NIN + k) * DOUT + oh)));
    }
}

// ---------------------------------------------------------------------------
// reduce_pass: one 512-thread block per (b,n). hat held in REGISTERS between
// the weighted-sum and bscore phases (rows kb+256j, parity half h); rows
// 1024..1151 go through a 4 KB LDS tail. LDS ~7 KB total.
// Fuses scale_coef(c), scale_coef(r), k-sum, squash, bscore, decoder layer-1.
// ---------------------------------------------------------------------------
template<bool COMPUTE>
__global__ __launch_bounds__(512, 4) void reduce_pass(
    const ushort* __restrict__ hatG,
    const void*   __restrict__ incRaw,
    const void*   __restrict__ wRaw,
    const ushort* __restrict__ bsPrev,
    const float*  __restrict__ partials,   // (NROWS, 16)
    int iter0,
    const ushort* __restrict__ W1c,
    const ushort* __restrict__ b1c,
    ushort* __restrict__ h1out,
    ushort* __restrict__ bsOut,
    void*   __restrict__ outFinal,
    const int* __restrict__ flagp)
{
    int bn  = blockIdx.x;
    int n   = bn % NOUTC;
    int b   = bn / NOUTC;
    int tid = threadIdx.x;

    __shared__ ushort wSb[NIN];               // 2.3 KB
    __shared__ float  redS[8][16];
    __shared__ float  sumS[16];
    __shared__ float  ocS[16];
    __shared__ float  scaleS;

    int h = tid & 1, kb = tid >> 1;           // kb in [0,256)
    int wave = tid >> 6, lane = tid & 63;

    uint4 v[4];                               // hat rows kb+256j, half h
    const ushort* tailS;                      // LDS view of rows 1024..1151

    if constexpr (!COMPUTE) {
        __shared__ uint4 hatTail4[256];       // 4 KB (rows 1024..1151)
        const ushort* hbase = hatG + (size_t)bn * NIN * DOUT;
        #pragma unroll
        for (int j = 0; j < 4; j++)
            v[j] = *(const uint4*)(hbase + ((kb + 256 * j) * DOUT + h * 8));
        if (tid < 256)
            hatTail4[tid] = *(const uint4*)(hbase + 1024 * DOUT + tid * 8);
        tailS = (const ushort*)hatTail4;
    } else {
        // fallback: compute hat into LDS from raw tensors (ws too small for hatG)
        __shared__ int cntS;
        __shared__ uint4 hatS4[NIN * DOUT / 8];   // 36 KB
        int isbf = detect_bf(wRaw, &cntS);
        size_t wnb = (size_t)n * NIN * DOUT * DIN;
        for (int idx = tid; idx < NIN * DOUT; idx += 512) {
            int k = idx >> 4;
            float s = 0.f;
            #pragma unroll
            for (int i = 0; i < 8; i++)
                s += ldin(wRaw, wnb + (size_t)idx * 8 + i, isbf) *
                     ldin(incRaw, ((size_t)b * NIN + k) * DIN + i, isbf);
            ((ushort*)hatS4)[idx] = f2bf(s);
        }
        __syncthreads();
        const ushort* hbase = (const ushort*)hatS4;
        #pragma unroll
        for (int j = 0; j < 4; j++)
            v[j] = *(const uint4*)(hbase + ((kb + 256 * j) * DOUT + h * 8));
        tailS = hbase + 1024 * DOUT;
    }

    // rc weights (overlaps with the in-flight hat loads)
    if (!iter0) {
        if (tid < 9) {
            float s = 0.f;
            #pragma unroll
            for (int j = 0; j < NBY3; j++)
                s += partials[(size_t)(b * NOUTC + tid) * 16 + j];
            sumS[tid] = -s;
        }
        __syncthreads();
        float mn = 1e30f, mx = -1e30f;
        #pragma unroll
        for (int n2 = 0; n2 < 9; n2++) {
            float vv = sumS[n2];
            mn = fminf(mn, vv); mx = fmaxf(mx, vv);
        }
        float den = fmaxf(mx - mn, 1e-6f);
        float rv = (n < 9) ? fmaxf((sumS[n] - mn) / den, 0.5f) : 0.5f;
        for (int k = tid; k < NIN; k += 512) {
            float c = 0.5f;
            if (n < 9) {
                float vv[9], mn2 = 1e30f, mx2 = -1e30f;
                #pragma unroll
                for (int n2 = 0; n2 < 9; n2++) {
                    vv[n2] = bf2f(bsPrev[(size_t)(b * NOUTC + n2) * NIN + k]);
                    mn2 = fminf(mn2, vv[n2]); mx2 = fmaxf(mx2, vv[n2]);
                }
                float den2 = fmaxf(mx2 - mn2, 1e-6f);
                c = fmaxf((vv[n] - mn2) / den2, 0.5f);
            }
            wSb[k] = f2bf(c * rv);
        }
    }
    __syncthreads();

    // weighted k-sum from registers (+ LDS tail)
    float acc[8];
    #pragma unroll
    for (int o = 0; o < 8; o++) acc[o] = 0.f;
    #pragma unroll
    for (int j = 0; j < 4; j++) {
        int k = kb + 256 * j;
        float w = iter0 ? 1.f : bf2f(wSb[k]);
        bf16x8 hv = frag_of(v[j]);
        #pragma unroll
        for (int o = 0; o < 8; o++) acc[o] += w * (float)hv[o];
    }
    if (tid < 256) {                          // tail rows 1024..1151
        int k = 1024 + kb;
        float w = iter0 ? 1.f : bf2f(wSb[k]);
        bf16x8 hv = ld_frag(tailS + kb * DOUT + h * 8);
        #pragma unroll
        for (int o = 0; o < 8; o++) acc[o] += w * (float)hv[o];
    }
    #pragma unroll
    for (int off = 32; off >= 2; off >>= 1) {
        #pragma unroll
        for (int o = 0; o < 8; o++) acc[o] += __shfl_xor(acc[o], off);
    }
    if (lane < 2) {
        #pragma unroll
        for (int o = 0; o < 8; o++) redS[wave][lane * 8 + o] = acc[o];
    }
    __syncthreads();
    if (tid < 16) {
        float s = 0.f;
        #pragma unroll
        for (int wv = 0; wv < 8; wv++) s += redS[wv][tid];
        sumS[tid] = s;
    }
    __syncthreads();
    if (tid == 0) {
        float n2 = 0.f;
        #pragma unroll
        for (int o = 0; o < 16; o++) n2 += sumS[o] * sumS[o];
        float nrm = sqrtf(n2);
        scaleS = n2 / (1.f + n2) / (nrm + 1e-8f);
    }
    __syncthreads();
    if (tid < 16) {
        float oc = scaleS * sumS[tid];
        ocS[tid] = oc;
        if (outFinal) {
            if (*flagp) ((ushort*)outFinal)[(size_t)bn * 16 + tid] = f2bf(oc);
            else        ((float*) outFinal)[(size_t)bn * 16 + tid] = oc;
        }
    }
    __syncthreads();

    // bscore from registers (+ LDS tail)
    if (bsOut) {
        float o0 = ocS[h * 8 + 0], o1 = ocS[h * 8 + 1], o2 = ocS[h * 8 + 2],
              o3 = ocS[h * 8 + 3], o4 = ocS[h * 8 + 4], o5 = ocS[h * 8 + 5],
              o6 = ocS[h * 8 + 6], o7 = ocS[h * 8 + 7];
        #pragma unroll
        for (int j = 0; j < 4; j++) {
            bf16x8 hv = frag_of(v[j]);
            float s = o0 * (float)hv[0] + o1 * (float)hv[1] + o2 * (float)hv[2] +
                      o3 * (float)hv[3] + o4 * (float)hv[4] + o5 * (float)hv[5] +
                      o6 * (float)hv[6] + o7 * (float)hv[7];
            s += __shfl_xor(s, 1);
            if (h == 0) bsOut[(size_t)bn * NIN + kb + 256 * j] = f2bf(s);
        }
        if (tid < 256) {
            bf16x8 hv = ld_frag(tailS + kb * DOUT + h * 8);
            float s = o0 * (float)hv[0] + o1 * (float)hv[1] + o2 * (float)hv[2] +
                      o3 * (float)hv[3] + o4 * (float)hv[4] + o5 * (float)hv[5] +
                      o6 * (float)hv[6] + o7 * (float)hv[7];
            s += __shfl_xor(s, 1);
            if (h == 0) bsOut[(size_t)bn * NIN + 1024 + kb] = f2bf(s);
        }
    }

    // fused decoder layer 1 (block-diagonal): one column per thread
    if (h1out) {
        int col = tid;
        float acc1 = bf2f(b1c[col]);
        #pragma unroll
        for (int i = 0; i < 16; i++)
            acc1 += ocS[i] * bf2f(W1c[(size_t)(n * 16 + i) * H1DIM + col]);
        h1out[(size_t)bn * H1DIM + col] = f2bf(fmaxf(acc1, 0.f));
    }
}

// ---------------------------------------------------------------------------
// 64x64-tile MFMA GEMM, register double-buffered staging, LDS rows padded
// to 40 ushorts (5 uint4) -> conflict-free fragment reads.
// ---------------------------------------------------------------------------
__global__ __launch_bounds__(256) void gemm_kernel(
    const ushort* __restrict__ A, const ushort* __restrict__ Bt,
    const ushort* __restrict__ bias, int K, int N,
    ushort* __restrict__ Cout,
    const ushort* __restrict__ xin, float* __restrict__ partials)
{
    int m0 = blockIdx.x * 64, n0 = blockIdx.y * 64;
    int tid = threadIdx.x;
    int wave = tid >> 6, lane = tid & 63, quad = lane >> 4, l16 = lane & 15;

    __shared__ uint4 As4[320];
    __shared__ uint4 Bs4[320];
    ushort* As = (ushort*)As4;
    ushort* Bs = (ushort*)Bs4;

    f32x4 acc[4];
    #pragma unroll
    for (int nt = 0; nt < 4; nt++)
        #pragma unroll
        for (int rg = 0; rg < 4; rg++) acc[nt][rg] = 0.f;

    int sMi = tid >> 2, sKk = (tid & 3) * 8;
    int sLds = sMi * 5 + (tid & 3);
    const ushort* Ap = A + (size_t)(m0 + sMi) * K + sKk;
    const ushort* Bp = Bt + (size_t)(n0 + sMi) * K + sKk;
    bool bOK = (n0 + sMi) < N;

    uint4 aR = *(const uint4*)Ap;
    uint4 bR = bOK ? *(const uint4*)Bp : make_uint4(0, 0, 0, 0);

    for (int k0 = 0; k0 < K; k0 += 32) {
        As4[sLds] = aR;
        Bs4[sLds] = bR;
        __syncthreads();
        if (k0 + 32 < K) {
            aR = *(const uint4*)(Ap + k0 + 32);
            bR = bOK ? *(const uint4*)(Bp + k0 + 32) : make_uint4(0, 0, 0, 0);
        }
        bf16x8 a = ld_frag(As + (wave * 16 + l16) * 40 + quad * 8);
        #pragma unroll
        for (int nt = 0; nt < 4; nt++) {
            bf16x8 bb = ld_frag(Bs + (nt * 16 + l16) * 40 + quad * 8);
            acc[nt] = __builtin_amdgcn_mfma_f32_16x16x32_bf16(a, bb, acc[nt], 0, 0, 0);
        }
        __syncthreads();
    }

    int rowBase = m0 + wave * 16 + quad * 4;
    if (Cout) {
        #pragma unroll
        for (int nt = 0; nt < 4; nt++) {
            int col = n0 + nt * 16 + l16;
            float bv = bf2f(bias[col]);
            #pragma unroll
            for (int rg = 0; rg < 4; rg++) {
                float v = acc[nt][rg] + bv;
                Cout[(size_t)(rowBase + rg) * N + col] = f2bf(fmaxf(v, 0.f));
            }
        }
    } else {
        float vr[4] = {0.f, 0.f, 0.f, 0.f};
        #pragma unroll
        for (int nt = 0; nt < 4; nt++) {
            int col = n0 + nt * 16 + l16;
            if (col < N) {
                float bv = bf2f(bias[col]);
                #pragma unroll
                for (int rg = 0; rg < 4; rg++) {
                    int row = rowBase + rg;
                    int bb = row / NOUTC;
                    float z = acc[nt][rg] + bv;
                    float s = 1.f / (1.f + __expf(-z));
                    float d = bf2f(xin[(size_t)bb * PIX + col]) - s;
                    vr[rg] += d * d;
                }
            }
        }
        #pragma unroll
        for (int rg = 0; rg < 4; rg++) {
            float v = vr[rg];
            #pragma unroll
            for (int off = 8; off >= 1; off >>= 1) v += __shfl_xor(v, off, 16);
            if (l16 == 0)
                partials[(size_t)(rowBase + rg) * 16 + blockIdx.y] = v;
        }
    }
}

// ---------------------------------------------------------------------------
extern "C" void kernel_launch(void* const* d_in, const int* in_sizes, int n_in,
                              void* d_out, int out_size, void* d_ws, size_t ws_size,
                              hipStream_t stream)
{
    const void* inc = d_in[0];
    const void* x   = d_in[1];
    const void* w   = d_in[2];
    const void* W1  = d_in[3];
    const void* b1  = d_in[4];
    const void* W2  = d_in[5];
    const void* b2  = d_in[6];
    const void* W3  = d_in[7];
    const void* b3  = d_in[8];

    char* p = (char*)d_ws;
    auto alloc = [&](size_t bytes) { void* r = p; p += (bytes + 255) & ~(size_t)255; return r; };
    int*    flagWS    = (int*)alloc(256);
    ushort* bsA       = (ushort*)alloc((size_t)NROWS * NIN * 2);
    ushort* bsB       = (ushort*)alloc((size_t)NROWS * NIN * 2);
    float*  partials  = (float*)alloc((size_t)NROWS * 16 * 4);
    ushort* h1WS      = (ushort*)alloc((size_t)NROWS * H1DIM * 2);
    ushort* h2WS      = (ushort*)alloc((size_t)NROWS * H2DIM * 2);
    ushort* W2T       = (ushort*)alloc((size_t)H2DIM * H1DIM * 2);
    ushort* W3T       = (ushort*)alloc((size_t)PIX * H2DIM * 2);
    ushort* W1c       = (ushort*)alloc((size_t)160 * H1DIM * 2);
    ushort* b1c       = (ushort*)alloc((size_t)H1DIM * 2);
    ushort* b2c       = (ushort*)alloc((size_t)H2DIM * 2);
    ushort* b3c       = (ushort*)alloc((size_t)PIX * 2);
    ushort* xc        = (ushort*)alloc((size_t)BATCH * PIX * 2);
    ushort* hatG      = (ushort*)alloc((size_t)NROWS * NIN * DOUT * 2);  // 47 MB, LAST
    bool haveHat = ((char*)hatG + (size_t)NROWS * NIN * DOUT * 2) <= ((char*)d_ws + ws_size);

    PrepArgs pa;
    pa.w = w;
    pa.src[0] = W1;  pa.dst[0] = W1c;  pa.n[0] = 160 * H1DIM;
    pa.src[1] = b1;  pa.dst[1] = b1c;  pa.n[1] = H1DIM;
    pa.src[2] = b2;  pa.dst[2] = b2c;  pa.n[2] = H2DIM;
    pa.src[3] = b3;  pa.dst[3] = b3c;  pa.n[3] = PIX;
    pa.src[4] = x;   pa.dst[4] = xc;   pa.n[4] = BATCH * PIX;
    pa.src[5] = W2;  pa.dst[5] = W2T;  pa.n[5] = 0;
    pa.src[6] = W3;  pa.dst[6] = W3T;  pa.n[6] = 0;
    pa.flag = flagWS;
    prep_kernel<<<dim3(800, 7), 256, 0, stream>>>(pa);

    if (haveHat) hat_build<<<dim3(9, 8, NOUTC), 256, 0, stream>>>(inc, w, hatG);

    // iter 0: rc = 1; writes bscore->bsA and fused layer-1 h1
    if (haveHat)
        reduce_pass<false><<<NROWS, 512, 0, stream>>>(
            hatG, inc, w, nullptr, nullptr, 1,
            W1c, b1c, h1WS, bsA, nullptr, flagWS);
    else
        reduce_pass<true><<<NROWS, 512, 0, stream>>>(
            nullptr, inc, w, nullptr, nullptr, 1,
            W1c, b1c, h1WS, bsA, nullptr, flagWS);

    for (int it = 0; it < 2; it++) {
        gemm_kernel<<<dim3(NROWS / 64, H2DIM / 64), 256, 0, stream>>>(
            h1WS, W2T, b2c, H1DIM, H2DIM, h2WS, nullptr, nullptr);
        gemm_kernel<<<dim3(NROWS / 64, NBY3), 256, 0, stream>>>(
            h2WS, W3T, b3c, H2DIM, PIX, nullptr, xc, partials);

        int last = (it == 1);
        const ushort* bsP = (it == 0) ? bsA : bsB;
        ushort* bsO       = last ? nullptr : bsB;
        ushort* h1o       = last ? nullptr : h1WS;
        void*   fin       = last ? d_out : nullptr;
        if (haveHat)
            reduce_pass<false><<<NROWS, 512, 0, stream>>>(
                hatG, inc, w, bsP, partials, 0,
                W1c, b1c, h1o, bsO, fin, flagWS);
        else
            reduce_pass<true><<<NROWS, 512, 0, stream>>>(
                nullptr, inc, w, bsP, partials, 0,
                W1c, b1c, h1o, bsO, fin, flagWS);
    }
}